// Round 7
// baseline (124.170 us; speedup 1.0000x reference)
//
#include <hip/hip_runtime.h>
#include <hip/hip_bf16.h>
#include <math.h>

constexpr int B = 4;
constexpr int N = 1024;
constexpr float NEGINF = -9000000000000000.0f;

// ---------- prep: 256 blocks (b x 16-row tile) x 256 thr.
//   pass1: hp = h@lin_w^T + lin_b (tile kept in LDS)
//   pass2: u = hp@W1^T, v = hp@W2^T, au = u.a, av = v.a, vT = v transposed
__global__ __launch_bounds__(256) void gat_prep(
    const float* __restrict__ h, const float* __restrict__ lin_w,
    const float* __restrict__ lin_b, const float* __restrict__ W_w,
    const float* __restrict__ a_g,
    float* __restrict__ hp, float* __restrict__ u_out, float* __restrict__ vT,
    float* __restrict__ au_out, float* __restrict__ av_out) {
  __shared__ float hs[64 * 18];    // [k][n] h^T tile (16 rows + pad)
  __shared__ float wl[64 * 68];    // [k][fo] = lin_w[fo][k]
  __shared__ float w1[64 * 68];    // [k][o]  = W_w[o][k]
  __shared__ float w2[64 * 68];    // [k][o]  = W_w[o][64+k]
  __shared__ float hpT[64 * 18];   // [f][n]
  __shared__ float vt_s[64 * 17];  // [o][n]
  __shared__ float ared[2][16 * 17];
  __shared__ float lb_s[64], a_s[64];

  const int b = blockIdx.x >> 6;
  const int n0 = (blockIdx.x & 63) << 4;
  const int tid = threadIdx.x;

  if (tid < 64) { lb_s[tid] = lin_b[tid]; a_s[tid] = a_g[tid]; }
  for (int idx = tid; idx < 1024; idx += 256) {
    const int r = idx >> 6, c = idx & 63;
    hs[c * 18 + r] = h[((b << 10) + n0 + r) * 64 + c];
  }
  for (int idx = tid; idx < 4096; idx += 256) {
    const int o = idx >> 6, f = idx & 63;
    wl[f * 68 + o] = lin_w[idx];
    w1[f * 68 + o] = W_w[o * 128 + f];
    w2[f * 68 + o] = W_w[o * 128 + 64 + f];
  }
  __syncthreads();

  const int tf = tid & 15, tn = tid >> 4;  // row tn, cols 4tf..4tf+3
  // ---- pass 1: hp ----
  float ahp[4];
#pragma unroll
  for (int r = 0; r < 4; ++r) ahp[r] = lb_s[tf * 4 + r];
#pragma unroll 8
  for (int k = 0; k < 64; ++k) {
    const float hv = hs[k * 18 + tn];
    const float4 l4 = *(const float4*)&wl[k * 68 + tf * 4];
    ahp[0] = fmaf(hv, l4.x, ahp[0]);
    ahp[1] = fmaf(hv, l4.y, ahp[1]);
    ahp[2] = fmaf(hv, l4.z, ahp[2]);
    ahp[3] = fmaf(hv, l4.w, ahp[3]);
  }
  const int row = (b << 10) + n0 + tn;
  *(float4*)&hp[row * 64 + tf * 4] = make_float4(ahp[0], ahp[1], ahp[2], ahp[3]);
#pragma unroll
  for (int r = 0; r < 4; ++r) hpT[(tf * 4 + r) * 18 + tn] = ahp[r];
  __syncthreads();

  // ---- pass 2: u, v ----
  float aU[4] = {0.f, 0.f, 0.f, 0.f}, aV[4] = {0.f, 0.f, 0.f, 0.f};
#pragma unroll 8
  for (int k = 0; k < 64; ++k) {
    const float hv = hpT[k * 18 + tn];
    const float4 u4 = *(const float4*)&w1[k * 68 + tf * 4];
    const float4 v4 = *(const float4*)&w2[k * 68 + tf * 4];
    aU[0] = fmaf(hv, u4.x, aU[0]);
    aU[1] = fmaf(hv, u4.y, aU[1]);
    aU[2] = fmaf(hv, u4.z, aU[2]);
    aU[3] = fmaf(hv, u4.w, aU[3]);
    aV[0] = fmaf(hv, v4.x, aV[0]);
    aV[1] = fmaf(hv, v4.y, aV[1]);
    aV[2] = fmaf(hv, v4.z, aV[2]);
    aV[3] = fmaf(hv, v4.w, aV[3]);
  }
  *(float4*)&u_out[row * 64 + tf * 4] = make_float4(aU[0], aU[1], aU[2], aU[3]);
  float aup = 0.f, avp = 0.f;
#pragma unroll
  for (int r = 0; r < 4; ++r) {
    vt_s[(tf * 4 + r) * 17 + tn] = aV[r];
    aup = fmaf(a_s[tf * 4 + r], aU[r], aup);
    avp = fmaf(a_s[tf * 4 + r], aV[r], avp);
  }
  ared[0][tn * 17 + tf] = aup;
  ared[1][tn * 17 + tf] = avp;
  __syncthreads();
  for (int idx = tid; idx < 1024; idx += 256) {
    const int f = idx >> 4, n = idx & 15;
    vT[(((b << 6) + f) << 10) + n0 + n] = vt_s[f * 17 + n];
  }
  if (tid < 32) {
    const int which = tid >> 4, rr = tid & 15;
    float s2 = 0.f;
#pragma unroll
    for (int t = 0; t < 16; ++t) s2 += ared[which][rr * 17 + t];
    if (which == 0) au_out[(b << 10) + n0 + rr] = s2;
    else av_out[(b << 10) + n0 + rr] = s2;
  }
}

// ---------- attn: e = 0.6(au+av)+0.4*sum_f a|u+v| -> mask -> softmax -> PV -> ELU
// 1024 blocks (b x 4-row tile) x 256 threads; thread owns j = 4*tid .. 4*tid+3.
__global__ __launch_bounds__(256) void gat_attn(
    const float* __restrict__ u_g, const float* __restrict__ vT,
    const float* __restrict__ hp, const int* __restrict__ adj,
    const float* __restrict__ a_g, const float* __restrict__ au_g,
    const float* __restrict__ av_g, float* __restrict__ out) {
  __shared__ float p_s[4 * 1024];  // [i][j] 16 KB (reused as reduction buffer)
  __shared__ float u_s[64 * 4];    // [f][i]
  __shared__ float a_s[64];
  __shared__ float au_s[4];
  __shared__ float wred[4][4];     // [wave][i]
  __shared__ float wsum[4][4];
  __shared__ float rinv_s[4];

  const int b = blockIdx.x >> 8;
  const int i0 = (blockIdx.x & 255) << 2;
  const int tid = threadIdx.x;
  const int lane = tid & 63, w = tid >> 6;
  const int j0 = tid << 2;

  if (tid < 64) a_s[tid] = a_g[tid];
  if (tid < 4) au_s[tid] = au_g[(b << 10) + i0 + tid];
  {
    const int i = tid >> 6, f = tid & 63;
    u_s[f * 4 + i] = u_g[((b << 10) + i0 + i) * 64 + f];
  }

  // Early independent loads: adj (HBM, ~900cy) and av issue now, consumed
  // after the ~4000cy phase-1 loop -> latency fully hidden.
  const int* adjb = adj + (((b << 10) + i0) << 10) + j0;
  int4 ad4[4];
#pragma unroll
  for (int i = 0; i < 4; ++i) ad4[i] = *(const int4*)&adjb[i << 10];
  const float4 av4 = *(const float4*)&av_g[(b << 10) + j0];

  __syncthreads();

  // ---- Phase 1: d[i][k] = sum_f a_f * |u_if + v_(j0+k)f| ----
  float e[4][4];
#pragma unroll
  for (int i = 0; i < 4; ++i)
#pragma unroll
    for (int k = 0; k < 4; ++k) e[i][k] = 0.f;

  const float* vb = vT + ((b << 6) << 10);
#pragma unroll 8
  for (int f = 0; f < 64; ++f) {
    const float af = a_s[f];
    const float4 v4 = *(const float4*)&vb[(f << 10) + j0];
    const float4 u4 = *(const float4*)&u_s[f * 4];
    const float uu[4] = {u4.x, u4.y, u4.z, u4.w};
    const float vv[4] = {v4.x, v4.y, v4.z, v4.w};
#pragma unroll
    for (int i = 0; i < 4; ++i)
#pragma unroll
      for (int k = 0; k < 4; ++k)
        e[i][k] = fmaf(af, fabsf(uu[i] + vv[k]), e[i][k]);
  }
  // e = 0.6(au+av) + 0.4 d, then adjacency mask
  const float avv[4] = {0.6f * av4.x, 0.6f * av4.y, 0.6f * av4.z, 0.6f * av4.w};
  float au6[4];
#pragma unroll
  for (int i = 0; i < 4; ++i) au6[i] = 0.6f * au_s[i];
#pragma unroll
  for (int i = 0; i < 4; ++i) {
    const int adv[4] = {ad4[i].x, ad4[i].y, ad4[i].z, ad4[i].w};
#pragma unroll
    for (int k = 0; k < 4; ++k) {
      const float ev = fmaf(0.4f, e[i][k], au6[i] + avv[k]);
      e[i][k] = adv[k] > 0 ? ev : NEGINF;
    }
  }

  // ---- Phase 2: softmax in registers ----
#pragma unroll
  for (int i = 0; i < 4; ++i) {
    float mm = fmaxf(fmaxf(e[i][0], e[i][1]), fmaxf(e[i][2], e[i][3]));
#pragma unroll
    for (int off = 32; off; off >>= 1) mm = fmaxf(mm, __shfl_xor(mm, off));
    if (lane == 0) wred[w][i] = mm;
  }
  __syncthreads();
#pragma unroll
  for (int i = 0; i < 4; ++i) {
    const float mi = fmaxf(fmaxf(wred[0][i], wred[1][i]),
                           fmaxf(wred[2][i], wred[3][i]));
#pragma unroll
    for (int k = 0; k < 4; ++k) e[i][k] = __expf(e[i][k] - mi);
    float ss = e[i][0] + e[i][1] + e[i][2] + e[i][3];
#pragma unroll
    for (int off = 32; off; off >>= 1) ss += __shfl_xor(ss, off);
    if (lane == 0) wsum[w][i] = ss;
  }
  __syncthreads();
  if (tid < 4)
    rinv_s[tid] = 1.0f / (wsum[0][tid] + wsum[1][tid] + wsum[2][tid] + wsum[3][tid]);
  // p to LDS: [i][j] planes, float4 stores at lane-stride 16B (conflict-free)
#pragma unroll
  for (int i = 0; i < 4; ++i)
    *(float4*)&p_s[(i << 10) + j0] = make_float4(e[i][0], e[i][1], e[i][2], e[i][3]);
  __syncthreads();

  // ---- Phase 3: h' = p @ hp ; thread = (f, j-group of 256) ----
  const int fl = tid & 63, g = tid >> 6;
  float acc[4] = {0.f, 0.f, 0.f, 0.f};
  const float* hpb = hp + (b << 16);
#pragma unroll 4
  for (int jj = g << 8; jj < (g << 8) + 256; jj += 4) {
    const float4 p0 = *(const float4*)&p_s[jj];
    const float4 p1 = *(const float4*)&p_s[1024 + jj];
    const float4 p2 = *(const float4*)&p_s[2048 + jj];
    const float4 p3 = *(const float4*)&p_s[3072 + jj];
    float hv[4];
#pragma unroll
    for (int t = 0; t < 4; ++t) hv[t] = hpb[((jj + t) << 6) + fl];
    acc[0] += p0.x * hv[0] + p0.y * hv[1] + p0.z * hv[2] + p0.w * hv[3];
    acc[1] += p1.x * hv[0] + p1.y * hv[1] + p1.z * hv[2] + p1.w * hv[3];
    acc[2] += p2.x * hv[0] + p2.y * hv[1] + p2.z * hv[2] + p2.w * hv[3];
    acc[3] += p3.x * hv[0] + p3.y * hv[1] + p3.z * hv[2] + p3.w * hv[3];
  }
  __syncthreads();  // p_s reads done; reuse as reduction buffer [g*4+i][f]
  float* red = p_s;
#pragma unroll
  for (int i = 0; i < 4; ++i) red[(((g << 2) + i) << 6) + fl] = acc[i];
  __syncthreads();
  {
    const int i = tid >> 6, f = tid & 63;
    float r = red[((i) << 6) + f] + red[((4 + i) << 6) + f] +
              red[((8 + i) << 6) + f] + red[((12 + i) << 6) + f];
    r *= rinv_s[i];
    out[((b << 10) + i0 + i) * 64 + f] = r > 0.f ? r : expm1f(r);
  }
}

extern "C" void kernel_launch(void* const* d_in, const int* in_sizes, int n_in,
                              void* d_out, int out_size, void* d_ws, size_t ws_size,
                              hipStream_t stream) {
  const float* h = (const float*)d_in[0];
  const int* adj = (const int*)d_in[1];
  const float* lin_w = (const float*)d_in[2];
  const float* lin_b = (const float*)d_in[3];
  const float* W_w = (const float*)d_in[4];
  const float* a = (const float*)d_in[5];
  float* outp = (float*)d_out;

  float* ws = (float*)d_ws;
  float* hp = ws;                 // 262144
  float* u = ws + 262144;         // 262144
  float* vT = ws + 524288;        // 262144
  float* au = ws + 786432;        // 4096
  float* av = ws + 790528;        // 4096

  gat_prep<<<dim3(256), dim3(256), 0, stream>>>(h, lin_w, lin_b, W_w, a,
                                                hp, u, vT, au, av);
  gat_attn<<<dim3(1024), dim3(256), 0, stream>>>(u, vT, hp, adj, a, au, av, outp);
}

// Round 9
// 123.114 us; speedup vs baseline: 1.0086x; 1.0086x over previous
//
#include <hip/hip_runtime.h>
#include <hip/hip_bf16.h>
#include <math.h>

constexpr int B = 4;
constexpr int N = 1024;
constexpr float NEGINF = -9000000000000000.0f;

// ---------- prep: 256 blocks (b x 16-row tile) x 256 thr.
//   pass1: hp = h@lin_w^T + lin_b (tile kept in LDS)
//   pass2: u = hp@W1^T, v = hp@W2^T, au = u.a, av = v.a, vT = v transposed
__global__ __launch_bounds__(256) void gat_prep(
    const float* __restrict__ h, const float* __restrict__ lin_w,
    const float* __restrict__ lin_b, const float* __restrict__ W_w,
    const float* __restrict__ a_g,
    float* __restrict__ hp, float* __restrict__ u_out, float* __restrict__ vT,
    float* __restrict__ au_out, float* __restrict__ av_out) {
  __shared__ float hs[64 * 18];    // [k][n] h^T tile (16 rows + pad)
  __shared__ float wl[64 * 68];    // [k][fo] = lin_w[fo][k]
  __shared__ float w1[64 * 68];    // [k][o]  = W_w[o][k]
  __shared__ float w2[64 * 68];    // [k][o]  = W_w[o][64+k]
  __shared__ float hpT[64 * 18];   // [f][n]
  __shared__ float vt_s[64 * 17];  // [o][n]
  __shared__ float ared[2][16 * 17];
  __shared__ float lb_s[64], a_s[64];

  const int b = blockIdx.x >> 6;
  const int n0 = (blockIdx.x & 63) << 4;
  const int tid = threadIdx.x;

  if (tid < 64) { lb_s[tid] = lin_b[tid]; a_s[tid] = a_g[tid]; }
  for (int idx = tid; idx < 1024; idx += 256) {
    const int r = idx >> 6, c = idx & 63;
    hs[c * 18 + r] = h[((b << 10) + n0 + r) * 64 + c];
  }
  for (int idx = tid; idx < 4096; idx += 256) {
    const int o = idx >> 6, f = idx & 63;
    wl[f * 68 + o] = lin_w[idx];
    w1[f * 68 + o] = W_w[o * 128 + f];
    w2[f * 68 + o] = W_w[o * 128 + 64 + f];
  }
  __syncthreads();

  const int tf = tid & 15, tn = tid >> 4;  // row tn, cols 4tf..4tf+3
  // ---- pass 1: hp ----
  float ahp[4];
#pragma unroll
  for (int r = 0; r < 4; ++r) ahp[r] = lb_s[tf * 4 + r];
#pragma unroll 8
  for (int k = 0; k < 64; ++k) {
    const float hv = hs[k * 18 + tn];
    const float4 l4 = *(const float4*)&wl[k * 68 + tf * 4];
    ahp[0] = fmaf(hv, l4.x, ahp[0]);
    ahp[1] = fmaf(hv, l4.y, ahp[1]);
    ahp[2] = fmaf(hv, l4.z, ahp[2]);
    ahp[3] = fmaf(hv, l4.w, ahp[3]);
  }
  const int row = (b << 10) + n0 + tn;
  *(float4*)&hp[row * 64 + tf * 4] = make_float4(ahp[0], ahp[1], ahp[2], ahp[3]);
#pragma unroll
  for (int r = 0; r < 4; ++r) hpT[(tf * 4 + r) * 18 + tn] = ahp[r];
  __syncthreads();

  // ---- pass 2: u, v ----
  float aU[4] = {0.f, 0.f, 0.f, 0.f}, aV[4] = {0.f, 0.f, 0.f, 0.f};
#pragma unroll 8
  for (int k = 0; k < 64; ++k) {
    const float hv = hpT[k * 18 + tn];
    const float4 u4 = *(const float4*)&w1[k * 68 + tf * 4];
    const float4 v4 = *(const float4*)&w2[k * 68 + tf * 4];
    aU[0] = fmaf(hv, u4.x, aU[0]);
    aU[1] = fmaf(hv, u4.y, aU[1]);
    aU[2] = fmaf(hv, u4.z, aU[2]);
    aU[3] = fmaf(hv, u4.w, aU[3]);
    aV[0] = fmaf(hv, v4.x, aV[0]);
    aV[1] = fmaf(hv, v4.y, aV[1]);
    aV[2] = fmaf(hv, v4.z, aV[2]);
    aV[3] = fmaf(hv, v4.w, aV[3]);
  }
  *(float4*)&u_out[row * 64 + tf * 4] = make_float4(aU[0], aU[1], aU[2], aU[3]);
  float aup = 0.f, avp = 0.f;
#pragma unroll
  for (int r = 0; r < 4; ++r) {
    vt_s[(tf * 4 + r) * 17 + tn] = aV[r];
    aup = fmaf(a_s[tf * 4 + r], aU[r], aup);
    avp = fmaf(a_s[tf * 4 + r], aV[r], avp);
  }
  ared[0][tn * 17 + tf] = aup;
  ared[1][tn * 17 + tf] = avp;
  __syncthreads();
  for (int idx = tid; idx < 1024; idx += 256) {
    const int f = idx >> 4, n = idx & 15;
    vT[(((b << 6) + f) << 10) + n0 + n] = vt_s[f * 17 + n];
  }
  if (tid < 32) {
    const int which = tid >> 4, rr = tid & 15;
    float s2 = 0.f;
#pragma unroll
    for (int t = 0; t < 16; ++t) s2 += ared[which][rr * 17 + t];
    if (which == 0) au_out[(b << 10) + n0 + rr] = s2;
    else av_out[(b << 10) + n0 + rr] = s2;
  }
}

// ---------- attn: e = 0.6(au+av)+0.4*sum_f a|u+v| -> mask -> softmax -> PV -> ELU
// 1024 blocks (b x 4-row tile) x 256 threads; thread owns j = 4*tid .. 4*tid+3.
// u, a, au are wave-uniform -> read via scalar pipe (no LDS staging, no barrier).
__global__ __launch_bounds__(256) void gat_attn(
    const float* __restrict__ u_g, const float* __restrict__ vT,
    const float* __restrict__ hp, const int* __restrict__ adj,
    const float* __restrict__ a_g, const float* __restrict__ au_g,
    const float* __restrict__ av_g, float* __restrict__ out) {
  __shared__ float p_s[4 * 1024];  // [i][j] 16 KB (reused as reduction buffer)
  __shared__ float wred[4][4];     // [wave][i]
  __shared__ float wsum[4][4];
  __shared__ float rinv_s[4];

  const int b = blockIdx.x >> 8;
  const int i0 = (blockIdx.x & 255) << 2;
  const int tid = threadIdx.x;
  const int lane = tid & 63, w = tid >> 6;
  const int j0 = tid << 2;

  const float* ub = u_g + (((b << 10) + i0) << 6);  // uniform base: u[i][f]

  // ---- Phase 1: d[i][k] = sum_f a_f * |u_if + v_(j0+k)f| ----
  float e[4][4];
#pragma unroll
  for (int i = 0; i < 4; ++i)
#pragma unroll
    for (int k = 0; k < 4; ++k) e[i][k] = 0.f;

  const float* vb = vT + ((b << 6) << 10) + j0;
#pragma unroll 8
  for (int f = 0; f < 64; ++f) {
    const float af = a_g[f];                        // s_load (uniform)
    const float4 v4 = *(const float4*)&vb[f << 10]; // vector L2 load
    float uu[4];
#pragma unroll
    for (int i = 0; i < 4; ++i) uu[i] = ub[(i << 6) + f];  // s_load (uniform)
    const float vv[4] = {v4.x, v4.y, v4.z, v4.w};
#pragma unroll
    for (int i = 0; i < 4; ++i)
#pragma unroll
      for (int k = 0; k < 4; ++k)
        e[i][k] = fmaf(af, fabsf(uu[i] + vv[k]), e[i][k]);
  }
  // e = 0.6(au+av) + 0.4 d, then adjacency mask (int4 per row)
  const float4 av4 = *(const float4*)&av_g[(b << 10) + j0];
  const float avv[4] = {0.6f * av4.x, 0.6f * av4.y, 0.6f * av4.z, 0.6f * av4.w};
  float au6[4];
#pragma unroll
  for (int i = 0; i < 4; ++i) au6[i] = 0.6f * au_g[(b << 10) + i0 + i];  // s_load
  const int* adjb = adj + (((b << 10) + i0) << 10) + j0;
#pragma unroll
  for (int i = 0; i < 4; ++i) {
    const int4 ad = *(const int4*)&adjb[i << 10];
    const int adv[4] = {ad.x, ad.y, ad.z, ad.w};
#pragma unroll
    for (int k = 0; k < 4; ++k) {
      const float ev = fmaf(0.4f, e[i][k], au6[i] + avv[k]);
      e[i][k] = adv[k] > 0 ? ev : NEGINF;
    }
  }

  // ---- Phase 2: softmax in registers ----
#pragma unroll
  for (int i = 0; i < 4; ++i) {
    float mm = fmaxf(fmaxf(e[i][0], e[i][1]), fmaxf(e[i][2], e[i][3]));
#pragma unroll
    for (int off = 32; off; off >>= 1) mm = fmaxf(mm, __shfl_xor(mm, off));
    if (lane == 0) wred[w][i] = mm;
  }
  __syncthreads();
#pragma unroll
  for (int i = 0; i < 4; ++i) {
    const float mi = fmaxf(fmaxf(wred[0][i], wred[1][i]),
                           fmaxf(wred[2][i], wred[3][i]));
#pragma unroll
    for (int k = 0; k < 4; ++k) e[i][k] = __expf(e[i][k] - mi);
    float ss = e[i][0] + e[i][1] + e[i][2] + e[i][3];
#pragma unroll
    for (int off = 32; off; off >>= 1) ss += __shfl_xor(ss, off);
    if (lane == 0) wsum[w][i] = ss;
  }
  __syncthreads();
  if (tid < 4)
    rinv_s[tid] = 1.0f / (wsum[0][tid] + wsum[1][tid] + wsum[2][tid] + wsum[3][tid]);
  // p to LDS: [i][j] planes, float4 stores at lane-stride 16B (conflict-free)
#pragma unroll
  for (int i = 0; i < 4; ++i)
    *(float4*)&p_s[(i << 10) + j0] = make_float4(e[i][0], e[i][1], e[i][2], e[i][3]);
  __syncthreads();

  // ---- Phase 3: h' = p @ hp ; thread = (f, j-group of 256) ----
  const int fl = tid & 63, g = tid >> 6;
  float acc[4] = {0.f, 0.f, 0.f, 0.f};
  const float* hpb = hp + (b << 16);
#pragma unroll 4
  for (int jj = g << 8; jj < (g << 8) + 256; jj += 4) {
    const float4 p0 = *(const float4*)&p_s[jj];
    const float4 p1 = *(const float4*)&p_s[1024 + jj];
    const float4 p2 = *(const float4*)&p_s[2048 + jj];
    const float4 p3 = *(const float4*)&p_s[3072 + jj];
    float hv[4];
#pragma unroll
    for (int t = 0; t < 4; ++t) hv[t] = hpb[((jj + t) << 6) + fl];
    acc[0] += p0.x * hv[0] + p0.y * hv[1] + p0.z * hv[2] + p0.w * hv[3];
    acc[1] += p1.x * hv[0] + p1.y * hv[1] + p1.z * hv[2] + p1.w * hv[3];
    acc[2] += p2.x * hv[0] + p2.y * hv[1] + p2.z * hv[2] + p2.w * hv[3];
    acc[3] += p3.x * hv[0] + p3.y * hv[1] + p3.z * hv[2] + p3.w * hv[3];
  }
  __syncthreads();  // p_s reads done; reuse as reduction buffer [g*4+i][f]
  float* red = p_s;
#pragma unroll
  for (int i = 0; i < 4; ++i) red[(((g << 2) + i) << 6) + fl] = acc[i];
  __syncthreads();
  {
    const int i = tid >> 6, f = tid & 63;
    float r = red[((i) << 6) + f] + red[((4 + i) << 6) + f] +
              red[((8 + i) << 6) + f] + red[((12 + i) << 6) + f];
    r *= rinv_s[i];
    out[((b << 10) + i0 + i) * 64 + f] = r > 0.f ? r : expm1f(r);
  }
}

extern "C" void kernel_launch(void* const* d_in, const int* in_sizes, int n_in,
                              void* d_out, int out_size, void* d_ws, size_t ws_size,
                              hipStream_t stream) {
  const float* h = (const float*)d_in[0];
  const int* adj = (const int*)d_in[1];
  const float* lin_w = (const float*)d_in[2];
  const float* lin_b = (const float*)d_in[3];
  const float* W_w = (const float*)d_in[4];
  const float* a = (const float*)d_in[5];
  float* outp = (float*)d_out;

  float* ws = (float*)d_ws;
  float* hp = ws;                 // 262144
  float* u = ws + 262144;         // 262144
  float* vT = ws + 524288;        // 262144
  float* au = ws + 786432;        // 4096
  float* av = ws + 790528;        // 4096

  gat_prep<<<dim3(256), dim3(256), 0, stream>>>(h, lin_w, lin_b, W_w, a,
                                                hp, u, vT, au, av);
  gat_attn<<<dim3(1024), dim3(256), 0, stream>>>(u, vT, hp, adj, a, au, av, outp);
}

// Round 10
// 111.467 us; speedup vs baseline: 1.1140x; 1.1045x over previous
//
#include <hip/hip_runtime.h>
#include <hip/hip_bf16.h>
#include <math.h>

constexpr int B = 4;
constexpr int N = 1024;
constexpr float NEGINF = -9000000000000000.0f;

// ---------- prep: 256 blocks (b x 16-row tile) x 256 thr.
//   pass1: hp = h@lin_w^T + lin_b (tile kept in LDS)
//   pass2: u = hp@W1^T, v = hp@W2^T, au = u.a, av = v.a, vT = v transposed
__global__ __launch_bounds__(256) void gat_prep(
    const float* __restrict__ h, const float* __restrict__ lin_w,
    const float* __restrict__ lin_b, const float* __restrict__ W_w,
    const float* __restrict__ a_g,
    float* __restrict__ hp, float* __restrict__ u_out, float* __restrict__ vT,
    float* __restrict__ au_out, float* __restrict__ av_out) {
  __shared__ float hs[64 * 18];    // [k][n] h^T tile (16 rows + pad)
  __shared__ float wl[64 * 68];    // [k][fo] = lin_w[fo][k]
  __shared__ float w1[64 * 68];    // [k][o]  = W_w[o][k]
  __shared__ float w2[64 * 68];    // [k][o]  = W_w[o][64+k]
  __shared__ float hpT[64 * 18];   // [f][n]
  __shared__ float vt_s[64 * 17];  // [o][n]
  __shared__ float ared[2][16 * 17];
  __shared__ float lb_s[64], a_s[64];

  const int b = blockIdx.x >> 6;
  const int n0 = (blockIdx.x & 63) << 4;
  const int tid = threadIdx.x;

  if (tid < 64) { lb_s[tid] = lin_b[tid]; a_s[tid] = a_g[tid]; }
  for (int idx = tid; idx < 1024; idx += 256) {
    const int r = idx >> 6, c = idx & 63;
    hs[c * 18 + r] = h[((b << 10) + n0 + r) * 64 + c];
  }
  for (int idx = tid; idx < 4096; idx += 256) {
    const int o = idx >> 6, f = idx & 63;
    wl[f * 68 + o] = lin_w[idx];
    w1[f * 68 + o] = W_w[o * 128 + f];
    w2[f * 68 + o] = W_w[o * 128 + 64 + f];
  }
  __syncthreads();

  const int tf = tid & 15, tn = tid >> 4;  // row tn, cols 4tf..4tf+3
  // ---- pass 1: hp ----
  float ahp[4];
#pragma unroll
  for (int r = 0; r < 4; ++r) ahp[r] = lb_s[tf * 4 + r];
#pragma unroll 8
  for (int k = 0; k < 64; ++k) {
    const float hv = hs[k * 18 + tn];
    const float4 l4 = *(const float4*)&wl[k * 68 + tf * 4];
    ahp[0] = fmaf(hv, l4.x, ahp[0]);
    ahp[1] = fmaf(hv, l4.y, ahp[1]);
    ahp[2] = fmaf(hv, l4.z, ahp[2]);
    ahp[3] = fmaf(hv, l4.w, ahp[3]);
  }
  const int row = (b << 10) + n0 + tn;
  *(float4*)&hp[row * 64 + tf * 4] = make_float4(ahp[0], ahp[1], ahp[2], ahp[3]);
#pragma unroll
  for (int r = 0; r < 4; ++r) hpT[(tf * 4 + r) * 18 + tn] = ahp[r];
  __syncthreads();

  // ---- pass 2: u, v ----
  float aU[4] = {0.f, 0.f, 0.f, 0.f}, aV[4] = {0.f, 0.f, 0.f, 0.f};
#pragma unroll 8
  for (int k = 0; k < 64; ++k) {
    const float hv = hpT[k * 18 + tn];
    const float4 u4 = *(const float4*)&w1[k * 68 + tf * 4];
    const float4 v4 = *(const float4*)&w2[k * 68 + tf * 4];
    aU[0] = fmaf(hv, u4.x, aU[0]);
    aU[1] = fmaf(hv, u4.y, aU[1]);
    aU[2] = fmaf(hv, u4.z, aU[2]);
    aU[3] = fmaf(hv, u4.w, aU[3]);
    aV[0] = fmaf(hv, v4.x, aV[0]);
    aV[1] = fmaf(hv, v4.y, aV[1]);
    aV[2] = fmaf(hv, v4.z, aV[2]);
    aV[3] = fmaf(hv, v4.w, aV[3]);
  }
  *(float4*)&u_out[row * 64 + tf * 4] = make_float4(aU[0], aU[1], aU[2], aU[3]);
  float aup = 0.f, avp = 0.f;
#pragma unroll
  for (int r = 0; r < 4; ++r) {
    vt_s[(tf * 4 + r) * 17 + tn] = aV[r];
    aup = fmaf(a_s[tf * 4 + r], aU[r], aup);
    avp = fmaf(a_s[tf * 4 + r], aV[r], avp);
  }
  ared[0][tn * 17 + tf] = aup;
  ared[1][tn * 17 + tf] = avp;
  __syncthreads();
  for (int idx = tid; idx < 1024; idx += 256) {
    const int f = idx >> 4, n = idx & 15;
    vT[(((b << 6) + f) << 10) + n0 + n] = vt_s[f * 17 + n];
  }
  if (tid < 32) {
    const int which = tid >> 4, rr = tid & 15;
    float s2 = 0.f;
#pragma unroll
    for (int t = 0; t < 16; ++t) s2 += ared[which][rr * 17 + t];
    if (which == 0) au_out[(b << 10) + n0 + rr] = s2;
    else av_out[(b << 10) + n0 + rr] = s2;
  }
}

// ---------- attn: e = 0.6(au+av)+0.4*sum_f a|u+v| -> mask -> softmax -> PV -> ELU
// 1024 blocks (b x 4-row tile) x 256 threads.
// Phase 1/2: thread owns j = 4*tid..4*tid+3 (round-6 proven form).
// Phase 3: thread = (f-quad, j-group of 64); p in swizzled [j][i] granules.
__global__ __launch_bounds__(256) void gat_attn(
    const float* __restrict__ u_g, const float* __restrict__ vT,
    const float* __restrict__ hp, const int* __restrict__ adj,
    const float* __restrict__ a_g, const float* __restrict__ au_g,
    const float* __restrict__ av_g, float* __restrict__ out) {
  __shared__ float p_s[4 * 1024];  // 16 KB: p granules, then reduction buffer
  __shared__ float u_s[64 * 4];    // [f][i]
  __shared__ float a_s[64];
  __shared__ float au_s[4];
  __shared__ float wred[4][4];     // [wave][i]
  __shared__ float wsum[4][4];
  __shared__ float rinv_s[4];

  const int b = blockIdx.x >> 8;
  const int i0 = (blockIdx.x & 255) << 2;
  const int tid = threadIdx.x;
  const int lane = tid & 63, w = tid >> 6;
  const int j0 = tid << 2;

  if (tid < 64) a_s[tid] = a_g[tid];
  if (tid < 4) au_s[tid] = au_g[(b << 10) + i0 + tid];
  {
    const int i = tid >> 6, f = tid & 63;
    u_s[f * 4 + i] = u_g[((b << 10) + i0 + i) * 64 + f];
  }
  __syncthreads();

  // ---- Phase 1: d[i][k] = sum_f a_f * |u_if + v_(j0+k)f| ----
  float e[4][4];
#pragma unroll
  for (int i = 0; i < 4; ++i)
#pragma unroll
    for (int k = 0; k < 4; ++k) e[i][k] = 0.f;

  const float* vb = vT + ((b << 6) << 10) + j0;
#pragma unroll 4
  for (int f = 0; f < 64; ++f) {
    const float af = a_s[f];
    const float4 v4 = *(const float4*)&vb[f << 10];
    const float4 u4 = *(const float4*)&u_s[f * 4];
    const float uu[4] = {u4.x, u4.y, u4.z, u4.w};
    const float vv[4] = {v4.x, v4.y, v4.z, v4.w};
#pragma unroll
    for (int i = 0; i < 4; ++i)
#pragma unroll
      for (int k = 0; k < 4; ++k)
        e[i][k] = fmaf(af, fabsf(uu[i] + vv[k]), e[i][k]);
  }
  // e = 0.6(au+av) + 0.4 d, then adjacency mask (int4 per row)
  const float4 av4 = *(const float4*)&av_g[(b << 10) + j0];
  const float avv[4] = {0.6f * av4.x, 0.6f * av4.y, 0.6f * av4.z, 0.6f * av4.w};
  float au6[4];
#pragma unroll
  for (int i = 0; i < 4; ++i) au6[i] = 0.6f * au_s[i];
  const int* adjb = adj + (((b << 10) + i0) << 10) + j0;
#pragma unroll
  for (int i = 0; i < 4; ++i) {
    const int4 ad = *(const int4*)&adjb[i << 10];
    const int adv[4] = {ad.x, ad.y, ad.z, ad.w};
#pragma unroll
    for (int k = 0; k < 4; ++k) {
      const float ev = fmaf(0.4f, e[i][k], au6[i] + avv[k]);
      e[i][k] = adv[k] > 0 ? ev : NEGINF;
    }
  }

  // ---- Phase 2: softmax in registers ----
#pragma unroll
  for (int i = 0; i < 4; ++i) {
    float mm = fmaxf(fmaxf(e[i][0], e[i][1]), fmaxf(e[i][2], e[i][3]));
#pragma unroll
    for (int off = 32; off; off >>= 1) mm = fmaxf(mm, __shfl_xor(mm, off));
    if (lane == 0) wred[w][i] = mm;
  }
  __syncthreads();
#pragma unroll
  for (int i = 0; i < 4; ++i) {
    const float mi = fmaxf(fmaxf(wred[0][i], wred[1][i]),
                           fmaxf(wred[2][i], wred[3][i]));
#pragma unroll
    for (int k = 0; k < 4; ++k) e[i][k] = __expf(e[i][k] - mi);
    float ss = e[i][0] + e[i][1] + e[i][2] + e[i][3];
#pragma unroll
    for (int off = 32; off; off >>= 1) ss += __shfl_xor(ss, off);
    if (lane == 0) wsum[w][i] = ss;
  }
  __syncthreads();
  if (tid < 4)
    rinv_s[tid] = 1.0f / (wsum[0][tid] + wsum[1][tid] + wsum[2][tid] + wsum[3][tid]);

  // p granules: j's 4 i-values at float index 4*(j>>2) + (j&3)*1024.
  // Store k: lane writes granule (tid + 256k) -> stride-1 granules, conflict-free.
#pragma unroll
  for (int k = 0; k < 4; ++k)
    *(float4*)&p_s[(tid << 2) + (k << 10)] =
        make_float4(e[0][k], e[1][k], e[2][k], e[3][k]);
  __syncthreads();

  // ---- Phase 3: h' = p @ hp ; thread = (f-quad fq, j-group g of 64) ----
  const int fq = tid & 15, g = tid >> 4;
  float4 acc[4];
#pragma unroll
  for (int i = 0; i < 4; ++i) acc[i] = make_float4(0.f, 0.f, 0.f, 0.f);
  const float* hpb = hp + (b << 16) + (fq << 2);
#pragma unroll 4
  for (int jj = 0; jj < 64; ++jj) {
    const int j = (g << 6) + jj;
    const float4 h4 = *(const float4*)&hpb[j << 6];
    const float4 p4 = *(const float4*)&p_s[(j & ~3) + ((j & 3) << 10)];
    acc[0].x = fmaf(p4.x, h4.x, acc[0].x);
    acc[0].y = fmaf(p4.x, h4.y, acc[0].y);
    acc[0].z = fmaf(p4.x, h4.z, acc[0].z);
    acc[0].w = fmaf(p4.x, h4.w, acc[0].w);
    acc[1].x = fmaf(p4.y, h4.x, acc[1].x);
    acc[1].y = fmaf(p4.y, h4.y, acc[1].y);
    acc[1].z = fmaf(p4.y, h4.z, acc[1].z);
    acc[1].w = fmaf(p4.y, h4.w, acc[1].w);
    acc[2].x = fmaf(p4.z, h4.x, acc[2].x);
    acc[2].y = fmaf(p4.z, h4.y, acc[2].y);
    acc[2].z = fmaf(p4.z, h4.z, acc[2].z);
    acc[2].w = fmaf(p4.z, h4.w, acc[2].w);
    acc[3].x = fmaf(p4.w, h4.x, acc[3].x);
    acc[3].y = fmaf(p4.w, h4.y, acc[3].y);
    acc[3].z = fmaf(p4.w, h4.z, acc[3].z);
    acc[3].w = fmaf(p4.w, h4.w, acc[3].w);
  }
  __syncthreads();  // p_s reads done; reuse as red[g][i][f] (16*4*64 = 16 KB)
#pragma unroll
  for (int i = 0; i < 4; ++i)
    *(float4*)&p_s[(g << 8) + (i << 6) + (fq << 2)] = acc[i];
  __syncthreads();
  {
    const int i = tid >> 6, f = tid & 63;
    float r = 0.f;
#pragma unroll
    for (int gg = 0; gg < 16; ++gg) r += p_s[(gg << 8) + (i << 6) + f];
    r *= rinv_s[i];
    out[((b << 10) + i0 + i) * 64 + f] = r > 0.f ? r : expm1f(r);
  }
}

extern "C" void kernel_launch(void* const* d_in, const int* in_sizes, int n_in,
                              void* d_out, int out_size, void* d_ws, size_t ws_size,
                              hipStream_t stream) {
  const float* h = (const float*)d_in[0];
  const int* adj = (const int*)d_in[1];
  const float* lin_w = (const float*)d_in[2];
  const float* lin_b = (const float*)d_in[3];
  const float* W_w = (const float*)d_in[4];
  const float* a = (const float*)d_in[5];
  float* outp = (float*)d_out;

  float* ws = (float*)d_ws;
  float* hp = ws;                 // 262144
  float* u = ws + 262144;         // 262144
  float* vT = ws + 524288;        // 262144
  float* au = ws + 786432;        // 4096
  float* av = ws + 790528;        // 4096

  gat_prep<<<dim3(256), dim3(256), 0, stream>>>(h, lin_w, lin_b, W_w, a,
                                                hp, u, vT, au, av);
  gat_attn<<<dim3(1024), dim3(256), 0, stream>>>(u, vT, hp, adj, a, au, av, outp);
}